// Round 2
// baseline (1562.673 us; speedup 1.0000x reference)
//
#include <hip/hip_runtime.h>
#include <hip/hip_bf16.h>
#include <math.h>

// ---------------- problem constants ----------------
static constexpr int CB     = 32;
static constexpr int CH     = 56;
static constexpr int CW     = 56;
static constexpr int CC     = 192;
static constexpr int CSHIFT = 3;
static constexpr int CN     = 49;
static constexpr int CNW    = 64;
static constexpr int CL     = CH * CW;            // 3136
static constexpr int CM     = CB * CNW * CN;      // 100352
static constexpr int CHID   = 768;

__device__ __forceinline__ float bfu2f(unsigned short u) {
  union { unsigned i; float f; } c; c.i = (unsigned)u << 16; return c.f;
}
__device__ __forceinline__ float bflo(unsigned u){ union{unsigned i; float f;} c; c.i = u << 16; return c.f; }
__device__ __forceinline__ float bfhi(unsigned u){ union{unsigned i; float f;} c; c.i = u & 0xffff0000u; return c.f; }

// ---------------- LN (optionally fused with roll + window partition), bf16 out ----------------
template<bool ROLL>
__global__ __launch_bounds__(256)
void ln_kernel(const float* __restrict__ xin, const float* __restrict__ gamma,
               const float* __restrict__ beta, __hip_bfloat16* __restrict__ out)
{
  const int wid = threadIdx.x >> 6, lane = threadIdx.x & 63;
  const int m = blockIdx.x * 4 + wid;
  size_t src;
  if (ROLL) {
    int b   = m / (CNW * CN);
    int rem = m - b * (CNW * CN);
    int nw  = rem / CN, t = rem - nw * CN;
    int wr = nw >> 3, wc = nw & 7;
    int ti = t / 7, tj = t - ti * 7;
    int sr = wr * 7 + ti + CSHIFT; if (sr >= CH) sr -= CH;
    int sc = wc * 7 + tj + CSHIFT; if (sc >= CW) sc -= CW;
    src = ((size_t)b * CL + (size_t)sr * CW + sc) * CC;
  } else {
    src = (size_t)m * CC;
  }
  float v0 = xin[src + lane], v1 = xin[src + lane + 64], v2 = xin[src + lane + 128];
  float s  = v0 + v1 + v2;
  float sq = v0 * v0 + v1 * v1 + v2 * v2;
  #pragma unroll
  for (int off = 32; off; off >>= 1) { s += __shfl_xor(s, off); sq += __shfl_xor(sq, off); }
  const float mu  = s * (1.0f / CC);
  const float inv = rsqrtf(sq * (1.0f / CC) - mu * mu + 1e-5f);
  const size_t dst = (size_t)m * CC;
  out[dst + lane      ] = __float2bfloat16((v0 - mu) * inv * gamma[lane      ] + beta[lane      ]);
  out[dst + lane + 64 ] = __float2bfloat16((v1 - mu) * inv * gamma[lane + 64 ] + beta[lane + 64 ]);
  out[dst + lane + 128] = __float2bfloat16((v2 - mu) * inv * gamma[lane + 128] + beta[lane + 128]);
}

// ---------------- 64x64-tile GEMM, A is bf16, W/bias fp32, fp32 FMA compute ----------------
// MODE 0: Out(bf16) = A@W + bias                         (qkv)
// MODE 1: Out[scatter(m)](f32) = resid[..] + A@W + bias  (proj + reverse + roll + residual)
// MODE 2: Out(bf16) = gelu(A@W + bias)                   (fc1)
// MODE 3: Out(f32) = resid + A@W + bias, resid may alias Out (fc2, in-place residual)
template<int MODE>
__global__ __launch_bounds__(256)
void gemm64(const __hip_bfloat16* __restrict__ Ain, const float* __restrict__ W,
            const float* __restrict__ bias, void* __restrict__ Outv,
            const float* __restrict__ resid, int M, int K, int Ncols)
{
  __shared__ float As[16][64];   // [k][row]
  __shared__ float Bs[16][64];   // [k][col]
  const int tid = threadIdx.x;
  const int row0 = blockIdx.y * 64, col0 = blockIdx.x * 64;
  const int ty = tid >> 4, tx = tid & 15;
  const int ar = tid >> 2, akq = tid & 3;
  const int bkr = tid >> 4, bcq = tid & 15;
  const unsigned short* A = (const unsigned short*)Ain;
  float acc[4][4] = {};
  for (int kk = 0; kk < K; kk += 16) {
    {
      const unsigned short* p = A + (size_t)(row0 + ar) * K + kk + akq * 4;
      uint2 u = *(const uint2*)p;
      As[akq * 4 + 0][ar] = bflo(u.x);
      As[akq * 4 + 1][ar] = bfhi(u.x);
      As[akq * 4 + 2][ar] = bflo(u.y);
      As[akq * 4 + 3][ar] = bfhi(u.y);
    }
    float4 b4 = *(const float4*)(W + (size_t)(kk + bkr) * Ncols + col0 + bcq * 4);
    *(float4*)&Bs[bkr][bcq * 4] = b4;
    __syncthreads();
    #pragma unroll
    for (int k = 0; k < 16; ++k) {
      float4 a = *(const float4*)&As[k][ty * 4];
      float4 b = *(const float4*)&Bs[k][tx * 4];
      float av[4] = {a.x, a.y, a.z, a.w};
      float bv[4] = {b.x, b.y, b.z, b.w};
      #pragma unroll
      for (int i = 0; i < 4; ++i)
        #pragma unroll
        for (int j = 0; j < 4; ++j)
          acc[i][j] = fmaf(av[i], bv[j], acc[i][j]);
    }
    __syncthreads();
  }

  if (MODE == 0) {
    __hip_bfloat16* Out = (__hip_bfloat16*)Outv;
    #pragma unroll
    for (int i = 0; i < 4; ++i) {
      size_t r = (size_t)(row0 + ty * 4 + i) * Ncols;
      #pragma unroll
      for (int j = 0; j < 4; ++j) {
        int col = col0 + tx * 4 + j;
        Out[r + col] = __float2bfloat16(acc[i][j] + bias[col]);
      }
    }
  } else if (MODE == 1) {
    float* Out = (float*)Outv;
    #pragma unroll
    for (int i = 0; i < 4; ++i) {
      int m = row0 + ty * 4 + i;
      int b = m / (CNW * CN);
      int rem = m - b * (CNW * CN);
      int nw = rem / CN, t = rem - nw * CN;
      int wr = nw >> 3, wc = nw & 7;
      int ti = t / 7, tj = t - ti * 7;
      int dr = wr * 7 + ti + CSHIFT; if (dr >= CH) dr -= CH;
      int dc = wc * 7 + tj + CSHIFT; if (dc >= CW) dc -= CW;
      size_t dst = ((size_t)b * CL + (size_t)dr * CW + dc) * CC;
      #pragma unroll
      for (int j = 0; j < 4; ++j) {
        int col = col0 + tx * 4 + j;
        Out[dst + col] = resid[dst + col] + acc[i][j] + bias[col];
      }
    }
  } else if (MODE == 2) {
    __hip_bfloat16* Out = (__hip_bfloat16*)Outv;
    #pragma unroll
    for (int i = 0; i < 4; ++i) {
      size_t r = (size_t)(row0 + ty * 4 + i) * Ncols;
      #pragma unroll
      for (int j = 0; j < 4; ++j) {
        int col = col0 + tx * 4 + j;
        float v = acc[i][j] + bias[col];
        float g = 0.5f * v * (1.0f + erff(v * 0.70710678118654752f));
        Out[r + col] = __float2bfloat16(g);
      }
    }
  } else {
    float* Out = (float*)Outv;
    #pragma unroll
    for (int i = 0; i < 4; ++i) {
      size_t r = (size_t)(row0 + ty * 4 + i) * Ncols;
      #pragma unroll
      for (int j = 0; j < 4; ++j) {
        int col = col0 + tx * 4 + j;
        Out[r + col] = resid[r + col] + acc[i][j] + bias[col];
      }
    }
  }
}

// ---------------- windowed attention: one block per (window, head), qkv bf16 in, bf16 out ----------------
__global__ __launch_bounds__(256)
void attn_kernel(const __hip_bfloat16* __restrict__ qkv, const float* __restrict__ bias_table,
                 __hip_bfloat16* __restrict__ attnout)
{
  __shared__ float qs[49 * 33];
  __shared__ float ks[49 * 33];
  __shared__ float vs[49 * 33];
  __shared__ float Ss[49 * 49];
  __shared__ float biasH[169];
  __shared__ int   reg[49];

  const int w = blockIdx.x / 6, h = blockIdx.x % 6;
  const int tid = threadIdx.x;
  const int nw = w & 63;
  const int wr = nw >> 3, wc = nw & 7;
  const float scale = 0.17677669529663687f;   // 32^-0.5
  const unsigned short* Q = (const unsigned short*)qkv;

  const size_t base = (size_t)w * 49 * 576 + h * 32;
  for (int e = tid; e < 49 * 32; e += 256) {
    int t = e >> 5, d = e & 31;
    size_t p = base + (size_t)t * 576 + d;
    qs[t * 33 + d] = bfu2f(Q[p]) * scale;
    ks[t * 33 + d] = bfu2f(Q[p + 192]);
    vs[t * 33 + d] = bfu2f(Q[p + 384]);
  }
  for (int e = tid; e < 169; e += 256) biasH[e] = bias_table[e * 6 + h];
  if (tid < 49) {
    int rr = wr * 7 + tid / 7, cc = wc * 7 + tid % 7;
    int hr = (rr < 49) ? 0 : ((rr < 53) ? 1 : 2);
    int hc = (cc < 49) ? 0 : ((cc < 53) ? 1 : 2);
    reg[tid] = hr * 3 + hc;
  }
  __syncthreads();

  for (int e = tid; e < 49 * 49; e += 256) {
    int i = e / 49, j = e - i * 49;
    float s = 0.0f;
    #pragma unroll 8
    for (int d = 0; d < 32; ++d) s = fmaf(qs[i * 33 + d], ks[j * 33 + d], s);
    int di = i / 7 - j / 7 + 6;
    int dj = i % 7 - j % 7 + 6;
    s += biasH[di * 13 + dj];
    if (reg[i] != reg[j]) s -= 100.0f;
    Ss[e] = s;
  }
  __syncthreads();

  const int wid = tid >> 6, lane = tid & 63;
  for (int r = wid; r < 49; r += 4) {
    float v = (lane < 49) ? Ss[r * 49 + lane] : -1e30f;
    float mx = v;
    #pragma unroll
    for (int off = 32; off; off >>= 1) mx = fmaxf(mx, __shfl_xor(mx, off));
    float e = (lane < 49) ? __expf(v - mx) : 0.0f;
    float sm = e;
    #pragma unroll
    for (int off = 32; off; off >>= 1) sm += __shfl_xor(sm, off);
    if (lane < 49) Ss[r * 49 + lane] = e / sm;
  }
  __syncthreads();

  for (int e = tid; e < 49 * 32; e += 256) {
    int i = e >> 5, d = e & 31;
    float s = 0.0f;
    #pragma unroll 7
    for (int j = 0; j < 49; ++j) s = fmaf(Ss[i * 49 + j], vs[j * 33 + d], s);
    attnout[((size_t)w * 49 + i) * 192 + h * 32 + d] = __float2bfloat16(s);
  }
}

// ---------------- launcher ----------------
extern "C" void kernel_launch(void* const* d_in, const int* in_sizes, int n_in,
                              void* d_out, int out_size, void* d_ws, size_t ws_size,
                              hipStream_t stream)
{
  const float* x        = (const float*)d_in[0];
  const float* n1g      = (const float*)d_in[1];
  const float* n1b      = (const float*)d_in[2];
  const float* qkv_w    = (const float*)d_in[3];
  const float* qkv_b    = (const float*)d_in[4];
  const float* btab     = (const float*)d_in[5];
  const float* proj_w   = (const float*)d_in[6];
  const float* proj_b   = (const float*)d_in[7];
  const float* n2g      = (const float*)d_in[8];
  const float* n2b      = (const float*)d_in[9];
  const float* fc1_w    = (const float*)d_in[10];
  const float* fc1_b    = (const float*)d_in[11];
  const float* fc2_w    = (const float*)d_in[12];
  const float* fc2_b    = (const float*)d_in[13];
  float* out = (float*)d_out;

  // workspace layout (bf16 intermediates): bufA 38.5 MB, bufB 154.2 MB => ~184 MiB total
  char* ws = (char*)d_ws;
  const size_t szA = (size_t)CM * CC * 2;          // xw -> attnout -> h2 (bf16)
  __hip_bfloat16* bufA = (__hip_bfloat16*)ws;
  __hip_bfloat16* bufB = (__hip_bfloat16*)(ws + szA);  // qkv (CM*576) -> hmid (CM*768), bf16

  // 1. LN1 + roll + window partition -> xw (bf16)
  ln_kernel<true><<<CM / 4, 256, 0, stream>>>(x, n1g, n1b, bufA);
  // 2. qkv = xw @ qkv_w + qkv_b -> bf16 [CM,576]
  gemm64<0><<<dim3(576 / 64, CM / 64), 256, 0, stream>>>(bufA, qkv_w, qkv_b, bufB, nullptr, CM, CC, 576);
  // 3. windowed attention -> attnout (bf16, reuses bufA)
  attn_kernel<<<2048 * 6, 256, 0, stream>>>(bufB, btab, bufA);
  // 4. proj + window reverse + roll + residual -> x2 directly into d_out (f32)
  gemm64<1><<<dim3(192 / 64, CM / 64), 256, 0, stream>>>(bufA, proj_w, proj_b, out, x, CM, CC, 192);
  // 5. LN2 on x2 -> h2 (bf16, bufA)
  ln_kernel<false><<<CM / 4, 256, 0, stream>>>(out, n2g, n2b, bufA);
  // 6. fc1 + gelu -> hmid (bf16, bufB)
  gemm64<2><<<dim3(CHID / 64, CM / 64), 256, 0, stream>>>(bufA, fc1_w, fc1_b, bufB, nullptr, CM, CC, CHID);
  // 7. fc2 + in-place residual: out = out + hmid @ fc2_w + fc2_b
  gemm64<3><<<dim3(192 / 64, CM / 64), 256, 0, stream>>>(bufB, fc2_w, fc2_b, out, out, CM, CHID, 192);
}

// Round 3
// 685.528 us; speedup vs baseline: 2.2795x; 2.2795x over previous
//
#include <hip/hip_runtime.h>
#include <hip/hip_bf16.h>
#include <math.h>

// ---------------- problem constants ----------------
static constexpr int CB     = 32;
static constexpr int CH     = 56;
static constexpr int CW     = 56;
static constexpr int CC     = 192;
static constexpr int CSHIFT = 3;
static constexpr int CN     = 49;
static constexpr int CNW    = 64;
static constexpr int CL     = CH * CW;            // 3136
static constexpr int CM     = CB * CNW * CN;      // 100352
static constexpr int CHID   = 768;

typedef __attribute__((ext_vector_type(8))) __bf16 bf16x8;
typedef __attribute__((ext_vector_type(4))) float  f32x4;

__device__ __forceinline__ float bfu2f(unsigned short u) {
  union { unsigned i; float f; } c; c.i = (unsigned)u << 16; return c.f;
}

#define GLOAD16(g, l) __builtin_amdgcn_global_load_lds( \
    (__attribute__((address_space(1))) void*)(g),       \
    (__attribute__((address_space(3))) void*)(l), 16, 0, 0)

// ---------------- weight transpose + fp32->bf16: Wt[n][k] = W[k][n] ----------------
__global__ __launch_bounds__(256)
void wconv_kernel(const float* __restrict__ W, __hip_bfloat16* __restrict__ Wt, int K, int N)
{
  int idx = blockIdx.x * 256 + threadIdx.x;
  if (idx >= K * N) return;
  int k = idx / N, n = idx - k * N;
  Wt[(size_t)n * K + k] = __float2bfloat16(W[idx]);
}

// ---------------- LN (optionally fused with roll + window partition), bf16 out ----------------
template<bool ROLL>
__global__ __launch_bounds__(256)
void ln_kernel(const float* __restrict__ xin, const float* __restrict__ gamma,
               const float* __restrict__ beta, __hip_bfloat16* __restrict__ out)
{
  const int wid = threadIdx.x >> 6, lane = threadIdx.x & 63;
  const int m = blockIdx.x * 4 + wid;
  size_t src;
  if (ROLL) {
    int b   = m / (CNW * CN);
    int rem = m - b * (CNW * CN);
    int nw  = rem / CN, t = rem - nw * CN;
    int wr = nw >> 3, wc = nw & 7;
    int ti = t / 7, tj = t - ti * 7;
    int sr = wr * 7 + ti + CSHIFT; if (sr >= CH) sr -= CH;
    int sc = wc * 7 + tj + CSHIFT; if (sc >= CW) sc -= CW;
    src = ((size_t)b * CL + (size_t)sr * CW + sc) * CC;
  } else {
    src = (size_t)m * CC;
  }
  float v0 = xin[src + lane], v1 = xin[src + lane + 64], v2 = xin[src + lane + 128];
  float s  = v0 + v1 + v2;
  float sq = v0 * v0 + v1 * v1 + v2 * v2;
  #pragma unroll
  for (int off = 32; off; off >>= 1) { s += __shfl_xor(s, off); sq += __shfl_xor(sq, off); }
  const float mu  = s * (1.0f / CC);
  const float inv = rsqrtf(sq * (1.0f / CC) - mu * mu + 1e-5f);
  const size_t dst = (size_t)m * CC;
  out[dst + lane      ] = __float2bfloat16((v0 - mu) * inv * gamma[lane      ] + beta[lane      ]);
  out[dst + lane + 64 ] = __float2bfloat16((v1 - mu) * inv * gamma[lane + 64 ] + beta[lane + 64 ]);
  out[dst + lane + 128] = __float2bfloat16((v2 - mu) * inv * gamma[lane + 128] + beta[lane + 128]);
}

// ---------------- MFMA bf16 GEMM: C[M,N] = A[M,K](bf16) @ Wt[N,K]^T(bf16) + bias ----------------
// Tile: BM=128, BN=64, BK=64. 4 waves (2x2), each wave 64x32 = 4x2 fragments 16x16.
// LDS linear layout, XOR-swizzled via pre-swizzled global source (slot ^= row&7).
// MODE 0: Out(bf16) = A@W + bias                          (qkv)
// MODE 1: Out[scatter(m)](f32) = resid[..] + A@W + bias   (proj + reverse + roll + residual)
// MODE 2: Out(bf16) = gelu(A@W + bias)                    (fc1)
// MODE 3: Out(f32) = resid + A@W + bias (resid aliases Out) (fc2)
template<int MODE>
__global__ __launch_bounds__(256)
void gemm_mfma(const __hip_bfloat16* __restrict__ Ain, const __hip_bfloat16* __restrict__ Wt,
               const float* __restrict__ bias, void* __restrict__ Outv,
               const float* __restrict__ resid, int K, int Ncols)
{
  __shared__ short As[128 * 64];   // 16 KB, row-major [128][64], swizzled slots
  __shared__ short Bs[64 * 64];    // 8 KB,  row-major [64][64],  swizzled slots

  const int tid  = threadIdx.x;
  const int lane = tid & 63, wid = tid >> 6;
  const int row0 = blockIdx.y * 128, col0 = blockIdx.x * 64;
  const int wm = wid >> 1, wn = wid & 1;
  const int lr = lane & 15, lg = lane >> 4;

  const short* A  = (const short*)Ain;
  const short* W  = (const short*)Wt;

  f32x4 acc[4][2] = {};

  for (int kk = 0; kk < K; kk += 64) {
    // stage A tile: 128 rows x 64 bf16 = 1024 chunks of 16B
    #pragma unroll
    for (int it = 0; it < 4; ++it) {
      int c = it * 256 + tid;
      int row = c >> 3, slot = c & 7;
      int kg = (slot ^ (row & 7)) * 8;
      GLOAD16(A + (size_t)(row0 + row) * K + kk + kg, As + c * 8);
    }
    // stage B tile: 64 rows x 64 bf16 = 512 chunks of 16B
    #pragma unroll
    for (int it = 0; it < 2; ++it) {
      int c = it * 256 + tid;
      int row = c >> 3, slot = c & 7;
      int kg = (slot ^ (row & 7)) * 8;
      GLOAD16(W + (size_t)(col0 + row) * K + kk + kg, Bs + c * 8);
    }
    __syncthreads();

    #pragma unroll
    for (int kh = 0; kh < 2; ++kh) {         // two K=32 halves
      const int sb = kh * 4 + lg;            // k-slot index before swizzle
      bf16x8 bfr[2];
      #pragma unroll
      for (int n = 0; n < 2; ++n) {
        int br = wn * 32 + n * 16 + lr;
        int slot = sb ^ (br & 7);
        bfr[n] = *(const bf16x8*)(Bs + br * 64 + slot * 8);
      }
      #pragma unroll
      for (int m = 0; m < 4; ++m) {
        int ar = wm * 64 + m * 16 + lr;
        int slot = sb ^ (ar & 7);
        bf16x8 afr = *(const bf16x8*)(As + ar * 64 + slot * 8);
        acc[m][0] = __builtin_amdgcn_mfma_f32_16x16x32_bf16(afr, bfr[0], acc[m][0], 0, 0, 0);
        acc[m][1] = __builtin_amdgcn_mfma_f32_16x16x32_bf16(afr, bfr[1], acc[m][1], 0, 0, 0);
      }
    }
    __syncthreads();
  }

  // epilogue: fragment (m,n): row = row0 + wm*64 + m*16 + lg*4 + r, col = col0 + wn*32 + n*16 + lr
  #pragma unroll
  for (int m = 0; m < 4; ++m) {
    const int rbase = row0 + wm * 64 + m * 16 + lg * 4;
    #pragma unroll
    for (int n = 0; n < 2; ++n) {
      const int col = col0 + wn * 32 + n * 16 + lr;
      const float bv = bias[col];
      #pragma unroll
      for (int r = 0; r < 4; ++r) {
        const int mrow = rbase + r;
        const float v = acc[m][n][r] + bv;
        if (MODE == 0) {
          ((__hip_bfloat16*)Outv)[(size_t)mrow * Ncols + col] = __float2bfloat16(v);
        } else if (MODE == 1) {
          int b = mrow / (CNW * CN);
          int rem = mrow - b * (CNW * CN);
          int nw = rem / CN, t = rem - nw * CN;
          int wr = nw >> 3, wc = nw & 7;
          int ti = t / 7, tj = t - ti * 7;
          int dr = wr * 7 + ti + CSHIFT; if (dr >= CH) dr -= CH;
          int dc = wc * 7 + tj + CSHIFT; if (dc >= CW) dc -= CW;
          size_t dst = ((size_t)b * CL + (size_t)dr * CW + dc) * CC + col;
          ((float*)Outv)[dst] = resid[dst] + v;
        } else if (MODE == 2) {
          float g = 0.5f * v * (1.0f + erff(v * 0.70710678118654752f));
          ((__hip_bfloat16*)Outv)[(size_t)mrow * Ncols + col] = __float2bfloat16(g);
        } else {
          size_t dst = (size_t)mrow * Ncols + col;
          ((float*)Outv)[dst] = resid[dst] + v;
        }
      }
    }
  }
}

// ---------------- windowed attention: one block per (window, head), bf16 in/out ----------------
__global__ __launch_bounds__(256)
void attn_kernel(const __hip_bfloat16* __restrict__ qkv, const float* __restrict__ bias_table,
                 __hip_bfloat16* __restrict__ attnout)
{
  __shared__ float qs[49 * 33];
  __shared__ float ks[49 * 33];
  __shared__ float vs[49 * 33];
  __shared__ float Ss[49 * 49];
  __shared__ float biasH[169];
  __shared__ int   reg[49];

  const int w = blockIdx.x / 6, h = blockIdx.x % 6;
  const int tid = threadIdx.x;
  const int nw = w & 63;
  const int wr = nw >> 3, wc = nw & 7;
  const float scale = 0.17677669529663687f;   // 32^-0.5
  const unsigned short* Q = (const unsigned short*)qkv;

  const size_t base = (size_t)w * 49 * 576 + h * 32;
  for (int e = tid; e < 49 * 32; e += 256) {
    int t = e >> 5, d = e & 31;
    size_t p = base + (size_t)t * 576 + d;
    qs[t * 33 + d] = bfu2f(Q[p]) * scale;
    ks[t * 33 + d] = bfu2f(Q[p + 192]);
    vs[t * 33 + d] = bfu2f(Q[p + 384]);
  }
  for (int e = tid; e < 169; e += 256) biasH[e] = bias_table[e * 6 + h];
  if (tid < 49) {
    int rr = wr * 7 + tid / 7, cc = wc * 7 + tid % 7;
    int hr = (rr < 49) ? 0 : ((rr < 53) ? 1 : 2);
    int hc = (cc < 49) ? 0 : ((cc < 53) ? 1 : 2);
    reg[tid] = hr * 3 + hc;
  }
  __syncthreads();

  for (int e = tid; e < 49 * 49; e += 256) {
    int i = e / 49, j = e - i * 49;
    float s = 0.0f;
    #pragma unroll 8
    for (int d = 0; d < 32; ++d) s = fmaf(qs[i * 33 + d], ks[j * 33 + d], s);
    int di = i / 7 - j / 7 + 6;
    int dj = i % 7 - j % 7 + 6;
    s += biasH[di * 13 + dj];
    if (reg[i] != reg[j]) s -= 100.0f;
    Ss[e] = s;
  }
  __syncthreads();

  const int wid = tid >> 6, lane = tid & 63;
  for (int r = wid; r < 49; r += 4) {
    float v = (lane < 49) ? Ss[r * 49 + lane] : -1e30f;
    float mx = v;
    #pragma unroll
    for (int off = 32; off; off >>= 1) mx = fmaxf(mx, __shfl_xor(mx, off));
    float e = (lane < 49) ? __expf(v - mx) : 0.0f;
    float sm = e;
    #pragma unroll
    for (int off = 32; off; off >>= 1) sm += __shfl_xor(sm, off);
    if (lane < 49) Ss[r * 49 + lane] = e / sm;
  }
  __syncthreads();

  for (int e = tid; e < 49 * 32; e += 256) {
    int i = e >> 5, d = e & 31;
    float s = 0.0f;
    #pragma unroll 7
    for (int j = 0; j < 49; ++j) s = fmaf(Ss[i * 49 + j], vs[j * 33 + d], s);
    attnout[((size_t)w * 49 + i) * 192 + h * 32 + d] = __float2bfloat16(s);
  }
}

// ---------------- launcher ----------------
extern "C" void kernel_launch(void* const* d_in, const int* in_sizes, int n_in,
                              void* d_out, int out_size, void* d_ws, size_t ws_size,
                              hipStream_t stream)
{
  const float* x        = (const float*)d_in[0];
  const float* n1g      = (const float*)d_in[1];
  const float* n1b      = (const float*)d_in[2];
  const float* qkv_w    = (const float*)d_in[3];
  const float* qkv_b    = (const float*)d_in[4];
  const float* btab     = (const float*)d_in[5];
  const float* proj_w   = (const float*)d_in[6];
  const float* proj_b   = (const float*)d_in[7];
  const float* n2g      = (const float*)d_in[8];
  const float* n2b      = (const float*)d_in[9];
  const float* fc1_w    = (const float*)d_in[10];
  const float* fc1_b    = (const float*)d_in[11];
  const float* fc2_w    = (const float*)d_in[12];
  const float* fc2_b    = (const float*)d_in[13];
  float* out = (float*)d_out;

  // workspace: bufA 38.5MB | bufB 154.1MB | transposed bf16 weights ~0.9MB => ~193.5MB
  char* ws = (char*)d_ws;
  const size_t szA = (size_t)CM * CC * 2;
  const size_t szB = (size_t)CM * CHID * 2;
  __hip_bfloat16* bufA = (__hip_bfloat16*)ws;                  // xw -> attnout -> h2
  __hip_bfloat16* bufB = (__hip_bfloat16*)(ws + szA);          // qkv -> hmid
  __hip_bfloat16* wq   = (__hip_bfloat16*)(ws + szA + szB);    // [576][192]
  __hip_bfloat16* wp   = wq + 576 * 192;                       // [192][192]
  __hip_bfloat16* w1   = wp + 192 * 192;                       // [768][192]
  __hip_bfloat16* w2   = w1 + 768 * 192;                       // [192][768]

  // 0. weight transpose/convert
  wconv_kernel<<<(192 * 576 + 255) / 256, 256, 0, stream>>>(qkv_w, wq, 192, 576);
  wconv_kernel<<<(192 * 192 + 255) / 256, 256, 0, stream>>>(proj_w, wp, 192, 192);
  wconv_kernel<<<(192 * 768 + 255) / 256, 256, 0, stream>>>(fc1_w, w1, 192, 768);
  wconv_kernel<<<(768 * 192 + 255) / 256, 256, 0, stream>>>(fc2_w, w2, 768, 192);

  // 1. LN1 + roll + window partition -> xw (bf16)
  ln_kernel<true><<<CM / 4, 256, 0, stream>>>(x, n1g, n1b, bufA);
  // 2. qkv = xw @ qkv_w + qkv_b -> bf16 [CM,576]
  gemm_mfma<0><<<dim3(576 / 64, CM / 128), 256, 0, stream>>>(bufA, wq, qkv_b, bufB, nullptr, CC, 576);
  // 3. windowed attention -> attnout (bf16, reuses bufA)
  attn_kernel<<<2048 * 6, 256, 0, stream>>>(bufB, btab, bufA);
  // 4. proj + window reverse + roll + residual -> x2 into d_out (f32)
  gemm_mfma<1><<<dim3(192 / 64, CM / 128), 256, 0, stream>>>(bufA, wp, proj_b, out, x, CC, 192);
  // 5. LN2 on x2 -> h2 (bf16, bufA)
  ln_kernel<false><<<CM / 4, 256, 0, stream>>>(out, n2g, n2b, bufA);
  // 6. fc1 + gelu -> hmid (bf16, bufB)
  gemm_mfma<2><<<dim3(CHID / 64, CM / 128), 256, 0, stream>>>(bufA, w1, fc1_b, bufB, nullptr, CC, CHID);
  // 7. fc2 + in-place residual: out += hmid @ fc2_w + fc2_b
  gemm_mfma<3><<<dim3(192 / 64, CM / 128), 256, 0, stream>>>(bufB, w2, fc2_b, out, out, CHID, 192);
}

// Round 4
// 420.017 us; speedup vs baseline: 3.7205x; 1.6321x over previous
//
#include <hip/hip_runtime.h>
#include <hip/hip_bf16.h>
#include <math.h>

// ---------------- problem constants ----------------
static constexpr int CB     = 32;
static constexpr int CH     = 56;
static constexpr int CW     = 56;
static constexpr int CC     = 192;
static constexpr int CSHIFT = 3;
static constexpr int CN     = 49;
static constexpr int CNW    = 64;
static constexpr int CL     = CH * CW;            // 3136
static constexpr int CM     = CB * CNW * CN;      // 100352
static constexpr int CHID   = 768;

typedef __attribute__((ext_vector_type(8))) __bf16 bf16x8;
typedef __attribute__((ext_vector_type(4))) float  f32x4;

__device__ __forceinline__ float bfu2f(unsigned short u) {
  union { unsigned i; float f; } c; c.i = (unsigned)u << 16; return c.f;
}
__device__ __forceinline__ unsigned short f2bu(float f) {
  __hip_bfloat16 b = __float2bfloat16(f);
  return *(unsigned short*)&b;
}

#define GLOAD16(g, l) __builtin_amdgcn_global_load_lds( \
    (__attribute__((address_space(1))) void*)(g),       \
    (__attribute__((address_space(3))) void*)(l), 16, 0, 0)

// ---------------- weight transpose + fp32->bf16: Wt[n][k] = W[k][n] ----------------
__global__ __launch_bounds__(256)
void wconv_kernel(const float* __restrict__ W, __hip_bfloat16* __restrict__ Wt, int K, int N)
{
  int idx = blockIdx.x * 256 + threadIdx.x;
  if (idx >= K * N) return;
  int k = idx / N, n = idx - k * N;
  Wt[(size_t)n * K + k] = __float2bfloat16(W[idx]);
}

// ---------------- bias2 table: [4 wtype][6 head][64 i][64 j] f32 ----------------
// value = rel-pos bias + shift-mask(-100) ; -inf for i>=49 or j>=49
__global__ __launch_bounds__(256)
void bias2_kernel(const float* __restrict__ bias_table, float* __restrict__ bias2)
{
  int idx = blockIdx.x * 256 + threadIdx.x;
  if (idx >= 4 * 6 * 64 * 64) return;
  int j = idx & 63, i = (idx >> 6) & 63;
  int rest = idx >> 12;
  int h = rest % 6, wt = rest / 6;
  float val;
  if (i >= 49 || j >= 49) {
    val = -INFINITY;
  } else {
    int ti = i / 7, ci = i - ti * 7;
    int tj = j / 7, cj = j - tj * 7;
    val = bias_table[((ti - tj + 6) * 13 + (ci - cj + 6)) * 6 + h];
    int hri = (wt & 2) ? ((ti < 4) ? 1 : 2) : 0;
    int hci = (wt & 1) ? ((ci < 4) ? 1 : 2) : 0;
    int hrj = (wt & 2) ? ((tj < 4) ? 1 : 2) : 0;
    int hcj = (wt & 1) ? ((cj < 4) ? 1 : 2) : 0;
    if (hri * 3 + hci != hrj * 3 + hcj) val -= 100.0f;
  }
  bias2[idx] = val;
}

// ---------------- LN (optionally fused with roll + window partition), bf16 out ----------------
template<bool ROLL>
__global__ __launch_bounds__(256)
void ln_kernel(const float* __restrict__ xin, const float* __restrict__ gamma,
               const float* __restrict__ beta, __hip_bfloat16* __restrict__ out)
{
  const int wid = threadIdx.x >> 6, lane = threadIdx.x & 63;
  const int m = blockIdx.x * 4 + wid;
  size_t src;
  if (ROLL) {
    int b   = m / (CNW * CN);
    int rem = m - b * (CNW * CN);
    int nw  = rem / CN, t = rem - nw * CN;
    int wr = nw >> 3, wc = nw & 7;
    int ti = t / 7, tj = t - ti * 7;
    int sr = wr * 7 + ti + CSHIFT; if (sr >= CH) sr -= CH;
    int sc = wc * 7 + tj + CSHIFT; if (sc >= CW) sc -= CW;
    src = ((size_t)b * CL + (size_t)sr * CW + sc) * CC;
  } else {
    src = (size_t)m * CC;
  }
  float v0 = xin[src + lane], v1 = xin[src + lane + 64], v2 = xin[src + lane + 128];
  float s  = v0 + v1 + v2;
  float sq = v0 * v0 + v1 * v1 + v2 * v2;
  #pragma unroll
  for (int off = 32; off; off >>= 1) { s += __shfl_xor(s, off); sq += __shfl_xor(sq, off); }
  const float mu  = s * (1.0f / CC);
  const float inv = rsqrtf(sq * (1.0f / CC) - mu * mu + 1e-5f);
  const size_t dst = (size_t)m * CC;
  out[dst + lane      ] = __float2bfloat16((v0 - mu) * inv * gamma[lane      ] + beta[lane      ]);
  out[dst + lane + 64 ] = __float2bfloat16((v1 - mu) * inv * gamma[lane + 64 ] + beta[lane + 64 ]);
  out[dst + lane + 128] = __float2bfloat16((v2 - mu) * inv * gamma[lane + 128] + beta[lane + 128]);
}

// ---------------- MFMA bf16 GEMM (unchanged from round 3) ----------------
template<int MODE>
__global__ __launch_bounds__(256)
void gemm_mfma(const __hip_bfloat16* __restrict__ Ain, const __hip_bfloat16* __restrict__ Wt,
               const float* __restrict__ bias, void* __restrict__ Outv,
               const float* __restrict__ resid, int K, int Ncols)
{
  __shared__ short As[128 * 64];
  __shared__ short Bs[64 * 64];

  const int tid  = threadIdx.x;
  const int lane = tid & 63, wid = tid >> 6;
  const int row0 = blockIdx.y * 128, col0 = blockIdx.x * 64;
  const int wm = wid >> 1, wn = wid & 1;
  const int lr = lane & 15, lg = lane >> 4;

  const short* A  = (const short*)Ain;
  const short* W  = (const short*)Wt;

  f32x4 acc[4][2] = {};

  for (int kk = 0; kk < K; kk += 64) {
    #pragma unroll
    for (int it = 0; it < 4; ++it) {
      int c = it * 256 + tid;
      int row = c >> 3, slot = c & 7;
      int kg = (slot ^ (row & 7)) * 8;
      GLOAD16(A + (size_t)(row0 + row) * K + kk + kg, As + c * 8);
    }
    #pragma unroll
    for (int it = 0; it < 2; ++it) {
      int c = it * 256 + tid;
      int row = c >> 3, slot = c & 7;
      int kg = (slot ^ (row & 7)) * 8;
      GLOAD16(W + (size_t)(col0 + row) * K + kk + kg, Bs + c * 8);
    }
    __syncthreads();

    #pragma unroll
    for (int kh = 0; kh < 2; ++kh) {
      const int sb = kh * 4 + lg;
      bf16x8 bfr[2];
      #pragma unroll
      for (int n = 0; n < 2; ++n) {
        int br = wn * 32 + n * 16 + lr;
        int slot = sb ^ (br & 7);
        bfr[n] = *(const bf16x8*)(Bs + br * 64 + slot * 8);
      }
      #pragma unroll
      for (int m = 0; m < 4; ++m) {
        int ar = wm * 64 + m * 16 + lr;
        int slot = sb ^ (ar & 7);
        bf16x8 afr = *(const bf16x8*)(As + ar * 64 + slot * 8);
        acc[m][0] = __builtin_amdgcn_mfma_f32_16x16x32_bf16(afr, bfr[0], acc[m][0], 0, 0, 0);
        acc[m][1] = __builtin_amdgcn_mfma_f32_16x16x32_bf16(afr, bfr[1], acc[m][1], 0, 0, 0);
      }
    }
    __syncthreads();
  }

  #pragma unroll
  for (int m = 0; m < 4; ++m) {
    const int rbase = row0 + wm * 64 + m * 16 + lg * 4;
    #pragma unroll
    for (int n = 0; n < 2; ++n) {
      const int col = col0 + wn * 32 + n * 16 + lr;
      const float bv = bias[col];
      #pragma unroll
      for (int r = 0; r < 4; ++r) {
        const int mrow = rbase + r;
        const float v = acc[m][n][r] + bv;
        if (MODE == 0) {
          ((__hip_bfloat16*)Outv)[(size_t)mrow * Ncols + col] = __float2bfloat16(v);
        } else if (MODE == 1) {
          int b = mrow / (CNW * CN);
          int rem = mrow - b * (CNW * CN);
          int nw = rem / CN, t = rem - nw * CN;
          int wr = nw >> 3, wc = nw & 7;
          int ti = t / 7, tj = t - ti * 7;
          int dr = wr * 7 + ti + CSHIFT; if (dr >= CH) dr -= CH;
          int dc = wc * 7 + tj + CSHIFT; if (dc >= CW) dc -= CW;
          size_t dst = ((size_t)b * CL + (size_t)dr * CW + dc) * CC + col;
          ((float*)Outv)[dst] = resid[dst] + v;
        } else if (MODE == 2) {
          float g = 0.5f * v * (1.0f + erff(v * 0.70710678118654752f));
          ((__hip_bfloat16*)Outv)[(size_t)mrow * Ncols + col] = __float2bfloat16(g);
        } else {
          size_t dst = (size_t)mrow * Ncols + col;
          ((float*)Outv)[dst] = resid[dst] + v;
        }
      }
    }
  }
}

// ---------------- MFMA windowed attention: one wave per (window, head) ----------------
// S^T = K @ Q^T (swapped -> softmax j-reduce is 2 shfl); P via LDS; V^T staged in LDS.
__global__ __launch_bounds__(64)
void attn_mfma_kernel(const __hip_bfloat16* __restrict__ qkv,
                      const float* __restrict__ bias2,
                      __hip_bfloat16* __restrict__ attnout)
{
  __shared__ unsigned short VT[32 * 72];   // V^T [d][tok], stride 72
  __shared__ unsigned short Pl[64 * 72];   // P  [i][j],   stride 72

  const int bid = blockIdx.x;
  const int w = bid / 6, h = bid - (bid / 6) * 6;
  const int lane = threadIdx.x;
  const int lr = lane & 15, lg = lane >> 4;
  const int nw = w & 63;
  const int wt = (((nw >> 3) == 7) ? 2 : 0) + (((nw & 7) == 7) ? 1 : 0);
  const unsigned short* Q = (const unsigned short*)qkv;
  const size_t rowbase = (size_t)w * 49 * 576;
  const float scale = 0.17677669529663687f;   // 32^-0.5

  // --- stage V^T (scalar transpose writes; t-major lanes => ~2-way bank) ---
  for (int e = lane; e < 196; e += 64) {
    int t = e % 49, c = e / 49;
    uint4 v = *(const uint4*)(Q + rowbase + (size_t)t * 576 + 384 + h * 32 + c * 8);
    unsigned va[4] = {v.x, v.y, v.z, v.w};
    #pragma unroll
    for (int q = 0; q < 4; ++q) {
      VT[(c * 8 + q * 2    ) * 72 + t] = (unsigned short)(va[q] & 0xffff);
      VT[(c * 8 + q * 2 + 1) * 72 + t] = (unsigned short)(va[q] >> 16);
    }
  }
  // zero V^T pad columns 49..63 (so P=0 x garbage never makes NaN)
  for (int e = lane; e < 32 * 15; e += 64) {
    int d = e / 15, t = 49 + e - (e / 15) * 15;
    VT[d * 72 + t] = 0;
  }

  // --- Q,K fragments straight from global (block-collectively coalesced) ---
  bf16x8 qf[4], kf[4];
  #pragma unroll
  for (int it = 0; it < 4; ++it) {
    int tok = it * 16 + lr; if (tok > 48) tok = 48;
    qf[it] = *(const bf16x8*)(Q + rowbase + (size_t)tok * 576 + h * 32 + lg * 8);
  }
  #pragma unroll
  for (int jt = 0; jt < 4; ++jt) {
    int tok = jt * 16 + lr; if (tok > 48) tok = 48;
    kf[jt] = *(const bf16x8*)(Q + rowbase + (size_t)tok * 576 + 192 + h * 32 + lg * 8);
  }

  // --- S^T = K @ Q^T : acc[jt][it], lane holds S[i = it*16+lr][j = jt*16+lg*4+r] ---
  f32x4 acc[4][4] = {};
  #pragma unroll
  for (int jt = 0; jt < 4; ++jt)
    #pragma unroll
    for (int it = 0; it < 4; ++it)
      acc[jt][it] = __builtin_amdgcn_mfma_f32_16x16x32_bf16(kf[jt], qf[it], acc[jt][it], 0, 0, 0);

  __syncthreads();   // V^T staged

  // --- scale + bias + mask, softmax over j (per it), P -> LDS bf16 ---
  const float* brow = bias2 + ((size_t)(wt * 6 + h) * 64) * 64;
  #pragma unroll
  for (int it = 0; it < 4; ++it) {
    const int i = it * 16 + lr;
    float s[4][4];
    #pragma unroll
    for (int jt = 0; jt < 4; ++jt) {
      float4 bv = *(const float4*)(brow + (size_t)i * 64 + jt * 16 + lg * 4);
      s[jt][0] = fmaf(acc[jt][it][0], scale, bv.x);
      s[jt][1] = fmaf(acc[jt][it][1], scale, bv.y);
      s[jt][2] = fmaf(acc[jt][it][2], scale, bv.z);
      s[jt][3] = fmaf(acc[jt][it][3], scale, bv.w);
    }
    float mx = s[0][0];
    #pragma unroll
    for (int jt = 0; jt < 4; ++jt)
      #pragma unroll
      for (int r = 0; r < 4; ++r) mx = fmaxf(mx, s[jt][r]);
    mx = fmaxf(mx, __shfl_xor(mx, 16));
    mx = fmaxf(mx, __shfl_xor(mx, 32));
    float sum = 0.0f;
    #pragma unroll
    for (int jt = 0; jt < 4; ++jt)
      #pragma unroll
      for (int r = 0; r < 4; ++r) { s[jt][r] = __expf(s[jt][r] - mx); sum += s[jt][r]; }
    sum += __shfl_xor(sum, 16);
    sum += __shfl_xor(sum, 32);
    const float inv = 1.0f / sum;
    #pragma unroll
    for (int jt = 0; jt < 4; ++jt) {
      unsigned lo = (unsigned)f2bu(s[jt][0] * inv) | ((unsigned)f2bu(s[jt][1] * inv) << 16);
      unsigned hi = (unsigned)f2bu(s[jt][2] * inv) | ((unsigned)f2bu(s[jt][3] * inv) << 16);
      uint2 val; val.x = lo; val.y = hi;
      *(uint2*)&Pl[i * 72 + jt * 16 + lg * 4] = val;
    }
  }

  __syncthreads();   // P visible

  // --- out = P @ V : K = 64 (2 steps) ---
  f32x4 o[4][2] = {};
  #pragma unroll
  for (int ks = 0; ks < 2; ++ks) {
    bf16x8 pa[4], vb[2];
    #pragma unroll
    for (int it = 0; it < 4; ++it)
      pa[it] = *(const bf16x8*)&Pl[(it * 16 + lr) * 72 + ks * 32 + lg * 8];
    #pragma unroll
    for (int nt = 0; nt < 2; ++nt)
      vb[nt] = *(const bf16x8*)&VT[(nt * 16 + lr) * 72 + ks * 32 + lg * 8];
    #pragma unroll
    for (int it = 0; it < 4; ++it) {
      o[it][0] = __builtin_amdgcn_mfma_f32_16x16x32_bf16(pa[it], vb[0], o[it][0], 0, 0, 0);
      o[it][1] = __builtin_amdgcn_mfma_f32_16x16x32_bf16(pa[it], vb[1], o[it][1], 0, 0, 0);
    }
  }

  // --- epilogue: row = it*16+lg*4+r, col = nt*16+lr ---
  #pragma unroll
  for (int it = 0; it < 4; ++it) {
    #pragma unroll
    for (int r = 0; r < 4; ++r) {
      int i = it * 16 + lg * 4 + r;
      if (i < 49) {
        size_t dst = ((size_t)w * 49 + i) * 192 + h * 32;
        attnout[dst + lr]      = __float2bfloat16(o[it][0][r]);
        attnout[dst + 16 + lr] = __float2bfloat16(o[it][1][r]);
      }
    }
  }
}

// ---------------- launcher ----------------
extern "C" void kernel_launch(void* const* d_in, const int* in_sizes, int n_in,
                              void* d_out, int out_size, void* d_ws, size_t ws_size,
                              hipStream_t stream)
{
  const float* x        = (const float*)d_in[0];
  const float* n1g      = (const float*)d_in[1];
  const float* n1b      = (const float*)d_in[2];
  const float* qkv_w    = (const float*)d_in[3];
  const float* qkv_b    = (const float*)d_in[4];
  const float* btab     = (const float*)d_in[5];
  const float* proj_w   = (const float*)d_in[6];
  const float* proj_b   = (const float*)d_in[7];
  const float* n2g      = (const float*)d_in[8];
  const float* n2b      = (const float*)d_in[9];
  const float* fc1_w    = (const float*)d_in[10];
  const float* fc1_b    = (const float*)d_in[11];
  const float* fc2_w    = (const float*)d_in[12];
  const float* fc2_b    = (const float*)d_in[13];
  float* out = (float*)d_out;

  char* ws = (char*)d_ws;
  const size_t szA = (size_t)CM * CC * 2;
  const size_t szB = (size_t)CM * CHID * 2;
  __hip_bfloat16* bufA = (__hip_bfloat16*)ws;                  // xw -> attnout -> h2
  __hip_bfloat16* bufB = (__hip_bfloat16*)(ws + szA);          // qkv -> hmid
  __hip_bfloat16* wq   = (__hip_bfloat16*)(ws + szA + szB);    // [576][192]
  __hip_bfloat16* wp   = wq + 576 * 192;                       // [192][192]
  __hip_bfloat16* w1   = wp + 192 * 192;                       // [768][192]
  __hip_bfloat16* w2   = w1 + 768 * 192;                       // [192][768]
  float* bias2         = (float*)(w2 + 192 * 768);             // [4][6][64][64] f32

  // 0. weight transpose/convert + bias table build
  wconv_kernel<<<(192 * 576 + 255) / 256, 256, 0, stream>>>(qkv_w, wq, 192, 576);
  wconv_kernel<<<(192 * 192 + 255) / 256, 256, 0, stream>>>(proj_w, wp, 192, 192);
  wconv_kernel<<<(192 * 768 + 255) / 256, 256, 0, stream>>>(fc1_w, w1, 192, 768);
  wconv_kernel<<<(768 * 192 + 255) / 256, 256, 0, stream>>>(fc2_w, w2, 768, 192);
  bias2_kernel<<<(4 * 6 * 64 * 64 + 255) / 256, 256, 0, stream>>>(btab, bias2);

  // 1. LN1 + roll + window partition -> xw (bf16)
  ln_kernel<true><<<CM / 4, 256, 0, stream>>>(x, n1g, n1b, bufA);
  // 2. qkv = xw @ qkv_w + qkv_b -> bf16 [CM,576]
  gemm_mfma<0><<<dim3(576 / 64, CM / 128), 256, 0, stream>>>(bufA, wq, qkv_b, bufB, nullptr, CC, 576);
  // 3. MFMA windowed attention -> attnout (bf16, reuses bufA)
  attn_mfma_kernel<<<2048 * 6, 64, 0, stream>>>(bufB, bias2, bufA);
  // 4. proj + window reverse + roll + residual -> x2 into d_out (f32)
  gemm_mfma<1><<<dim3(192 / 64, CM / 128), 256, 0, stream>>>(bufA, wp, proj_b, out, x, CC, 192);
  // 5. LN2 on x2 -> h2 (bf16, bufA)
  ln_kernel<false><<<CM / 4, 256, 0, stream>>>(out, n2g, n2b, bufA);
  // 6. fc1 + gelu -> hmid (bf16, bufB)
  gemm_mfma<2><<<dim3(CHID / 64, CM / 128), 256, 0, stream>>>(bufA, w1, fc1_b, bufB, nullptr, CC, CHID);
  // 7. fc2 + in-place residual: out += hmid @ fc2_w + fc2_b
  gemm_mfma<3><<<dim3(192 / 64, CM / 128), 256, 0, stream>>>(bufB, w2, fc2_b, out, out, CHID, 192);
}

// Round 5
// 349.458 us; speedup vs baseline: 4.4717x; 1.2019x over previous
//
#include <hip/hip_runtime.h>
#include <hip/hip_bf16.h>
#include <math.h>

// ---------------- problem constants ----------------
static constexpr int CB     = 32;
static constexpr int CH     = 56;
static constexpr int CW     = 56;
static constexpr int CC     = 192;
static constexpr int CSHIFT = 3;
static constexpr int CN     = 49;
static constexpr int CNW    = 64;
static constexpr int CL     = CH * CW;            // 3136
static constexpr int CM     = CB * CNW * CN;      // 100352
static constexpr int CHID   = 768;

typedef __attribute__((ext_vector_type(8))) __bf16 bf16x8;
typedef __attribute__((ext_vector_type(4))) float  f32x4;

__device__ __forceinline__ float bfu2f(unsigned short u) {
  union { unsigned i; float f; } c; c.i = (unsigned)u << 16; return c.f;
}
__device__ __forceinline__ unsigned short f2bu(float f) {
  __hip_bfloat16 b = __float2bfloat16(f);
  return *(unsigned short*)&b;
}
// tanh-form GELU, ~12 VALU instrs; |err| vs exact erf-GELU ~1e-3 (<< bf16 quantum here)
__device__ __forceinline__ float gelu_fast(float v) {
  float s  = v * v;
  float u2 = v * fmaf(s, 0.0713548163f, 1.5957691216f);   // 2 * 0.79788456*(v + 0.044715 v^3)
  float e  = __expf(u2);
  float t  = 1.0f - __fdividef(2.0f, e + 1.0f);           // tanh(u)
  float h  = 0.5f * v;
  return fmaf(h, t, h);
}

#define GLOAD16(g, l) __builtin_amdgcn_global_load_lds( \
    (__attribute__((address_space(1))) void*)(g),       \
    (__attribute__((address_space(3))) void*)(l), 16, 0, 0)

// ---------------- one-shot prep: 4 weight transposes (fp32->bf16) + bias2 table ----------------
// bias2[wt][h][i][j] = rel-pos bias + shift-mask(-100); -inf for i>=49 or j>=49
__global__ __launch_bounds__(256)
void prep_kernel(const float* __restrict__ qkv_w, const float* __restrict__ proj_w,
                 const float* __restrict__ fc1_w, const float* __restrict__ fc2_w,
                 const float* __restrict__ btab,
                 __hip_bfloat16* __restrict__ wq, __hip_bfloat16* __restrict__ wp,
                 __hip_bfloat16* __restrict__ w1, __hip_bfloat16* __restrict__ w2,
                 float* __restrict__ bias2)
{
  int idx = blockIdx.x * 256 + threadIdx.x;
  if (idx < 110592) {                       // wq: [192][576] -> [576][192]
    int k = idx / 576, n = idx - k * 576;
    wq[n * 192 + k] = __float2bfloat16(qkv_w[idx]);
    return;
  }
  idx -= 110592;
  if (idx < 36864) {                        // wp: [192][192]
    int k = idx / 192, n = idx - k * 192;
    wp[n * 192 + k] = __float2bfloat16(proj_w[idx]);
    return;
  }
  idx -= 36864;
  if (idx < 147456) {                       // w1: [192][768] -> [768][192]
    int k = idx / 768, n = idx - k * 768;
    w1[n * 192 + k] = __float2bfloat16(fc1_w[idx]);
    return;
  }
  idx -= 147456;
  if (idx < 147456) {                       // w2: [768][192] -> [192][768]
    int k = idx / 192, n = idx - k * 192;
    w2[n * 768 + k] = __float2bfloat16(fc2_w[idx]);
    return;
  }
  idx -= 147456;
  if (idx < 98304) {                        // bias2: [4][6][64][64]
    int j = idx & 63, i = (idx >> 6) & 63;
    int rest = idx >> 12;
    int h = rest % 6, wt = rest / 6;
    float val;
    if (i >= 49 || j >= 49) {
      val = -INFINITY;
    } else {
      int ti = i / 7, ci = i - ti * 7;
      int tj = j / 7, cj = j - tj * 7;
      val = btab[((ti - tj + 6) * 13 + (ci - cj + 6)) * 6 + h];
      int hri = (wt & 2) ? ((ti < 4) ? 1 : 2) : 0;
      int hci = (wt & 1) ? ((ci < 4) ? 1 : 2) : 0;
      int hrj = (wt & 2) ? ((tj < 4) ? 1 : 2) : 0;
      int hcj = (wt & 1) ? ((cj < 4) ? 1 : 2) : 0;
      if (hri * 3 + hci != hrj * 3 + hcj) val -= 100.0f;
    }
    bias2[idx] = val;
  }
}

// ---------------- LN (optionally fused with roll + window partition), bf16 out ----------------
template<bool ROLL>
__global__ __launch_bounds__(256)
void ln_kernel(const float* __restrict__ xin, const float* __restrict__ gamma,
               const float* __restrict__ beta, __hip_bfloat16* __restrict__ out)
{
  const int wid = threadIdx.x >> 6, lane = threadIdx.x & 63;
  const int m = blockIdx.x * 4 + wid;
  size_t src;
  if (ROLL) {
    int b   = m / (CNW * CN);
    int rem = m - b * (CNW * CN);
    int nw  = rem / CN, t = rem - nw * CN;
    int wr = nw >> 3, wc = nw & 7;
    int ti = t / 7, tj = t - ti * 7;
    int sr = wr * 7 + ti + CSHIFT; if (sr >= CH) sr -= CH;
    int sc = wc * 7 + tj + CSHIFT; if (sc >= CW) sc -= CW;
    src = ((size_t)b * CL + (size_t)sr * CW + sc) * CC;
  } else {
    src = (size_t)m * CC;
  }
  float v0 = xin[src + lane], v1 = xin[src + lane + 64], v2 = xin[src + lane + 128];
  float s  = v0 + v1 + v2;
  float sq = v0 * v0 + v1 * v1 + v2 * v2;
  #pragma unroll
  for (int off = 32; off; off >>= 1) { s += __shfl_xor(s, off); sq += __shfl_xor(sq, off); }
  const float mu  = s * (1.0f / CC);
  const float inv = rsqrtf(sq * (1.0f / CC) - mu * mu + 1e-5f);
  const size_t dst = (size_t)m * CC;
  out[dst + lane      ] = __float2bfloat16((v0 - mu) * inv * gamma[lane      ] + beta[lane      ]);
  out[dst + lane + 64 ] = __float2bfloat16((v1 - mu) * inv * gamma[lane + 64 ] + beta[lane + 64 ]);
  out[dst + lane + 128] = __float2bfloat16((v2 - mu) * inv * gamma[lane + 128] + beta[lane + 128]);
}

// ---------------- MFMA bf16 GEMM: C[M,N] = A[M,K] @ Wt[N,K]^T + bias ----------------
// BM=128, BN=64, BK=64, 4 waves. XCD-chunked block swizzle (grids all %8==0).
// MODE 0: Out(bf16) = A@W + bias                          (qkv)
// MODE 1: Out[scatter(m)](f32) = resid[..] + A@W + bias   (proj + reverse + roll + residual)
// MODE 2: Out(bf16) = gelu(A@W + bias)                    (fc1)
// MODE 3: Out(f32) = resid + A@W + bias (resid aliases Out) (fc2)
template<int MODE>
__global__ __launch_bounds__(256)
void gemm_mfma(const __hip_bfloat16* __restrict__ Ain, const __hip_bfloat16* __restrict__ Wt,
               const float* __restrict__ bias, void* __restrict__ Outv,
               const float* __restrict__ resid, int K, int Ncols)
{
  __shared__ short As[128 * 64];
  __shared__ short Bs[64 * 64];

  const int tid  = threadIdx.x;
  const int lane = tid & 63, wid = tid >> 6;

  // XCD-chunked swizzle: each XCD owns a contiguous span of (col,row) tiles
  const int nbx = gridDim.x;
  const int nwg = nbx * gridDim.y;
  const int wg  = blockIdx.y * nbx + blockIdx.x;
  const int swz = (wg & 7) * (nwg >> 3) + (wg >> 3);
  const int row0 = (swz / nbx) * 128, col0 = (swz % nbx) * 64;

  const int wm = wid >> 1, wn = wid & 1;
  const int lr = lane & 15, lg = lane >> 4;

  const short* A  = (const short*)Ain;
  const short* W  = (const short*)Wt;

  f32x4 acc[4][2] = {};

  for (int kk = 0; kk < K; kk += 64) {
    #pragma unroll
    for (int it = 0; it < 4; ++it) {
      int c = it * 256 + tid;
      int row = c >> 3, slot = c & 7;
      int kg = (slot ^ (row & 7)) * 8;
      GLOAD16(A + (size_t)(row0 + row) * K + kk + kg, As + c * 8);
    }
    #pragma unroll
    for (int it = 0; it < 2; ++it) {
      int c = it * 256 + tid;
      int row = c >> 3, slot = c & 7;
      int kg = (slot ^ (row & 7)) * 8;
      GLOAD16(W + (size_t)(col0 + row) * K + kk + kg, Bs + c * 8);
    }
    __syncthreads();

    #pragma unroll
    for (int kh = 0; kh < 2; ++kh) {
      const int sb = kh * 4 + lg;
      bf16x8 bfr[2];
      #pragma unroll
      for (int n = 0; n < 2; ++n) {
        int br = wn * 32 + n * 16 + lr;
        int slot = sb ^ (br & 7);
        bfr[n] = *(const bf16x8*)(Bs + br * 64 + slot * 8);
      }
      #pragma unroll
      for (int m = 0; m < 4; ++m) {
        int ar = wm * 64 + m * 16 + lr;
        int slot = sb ^ (ar & 7);
        bf16x8 afr = *(const bf16x8*)(As + ar * 64 + slot * 8);
        acc[m][0] = __builtin_amdgcn_mfma_f32_16x16x32_bf16(afr, bfr[0], acc[m][0], 0, 0, 0);
        acc[m][1] = __builtin_amdgcn_mfma_f32_16x16x32_bf16(afr, bfr[1], acc[m][1], 0, 0, 0);
      }
    }
    __syncthreads();
  }

  // epilogue: col = col0 + wn*32 + {0,16} + lr ; row = row0 + wm*64 + m*16 + lg*4 + r
  const int colA = col0 + wn * 32 + lr;
  const float bv0 = bias[colA];
  const float bv1 = bias[colA + 16];
  #pragma unroll
  for (int m = 0; m < 4; ++m) {
    #pragma unroll
    for (int r = 0; r < 4; ++r) {
      const int mrow = row0 + wm * 64 + m * 16 + lg * 4 + r;
      const float v0 = acc[m][0][r] + bv0;
      const float v1 = acc[m][1][r] + bv1;
      if (MODE == 0) {
        __hip_bfloat16* O = (__hip_bfloat16*)Outv;
        const size_t rr = (size_t)mrow * Ncols;
        O[rr + colA]      = __float2bfloat16(v0);
        O[rr + colA + 16] = __float2bfloat16(v1);
      } else if (MODE == 1) {
        int b = mrow / (CNW * CN);
        int rem = mrow - b * (CNW * CN);
        int nw = rem / CN, t = rem - nw * CN;
        int wr = nw >> 3, wc = nw & 7;
        int ti = t / 7, tj = t - ti * 7;
        int dr = wr * 7 + ti + CSHIFT; if (dr >= CH) dr -= CH;
        int dc = wc * 7 + tj + CSHIFT; if (dc >= CW) dc -= CW;
        const size_t dst = ((size_t)b * CL + (size_t)dr * CW + dc) * CC;
        float* O = (float*)Outv;
        O[dst + colA]      = resid[dst + colA]      + v0;
        O[dst + colA + 16] = resid[dst + colA + 16] + v1;
      } else if (MODE == 2) {
        __hip_bfloat16* O = (__hip_bfloat16*)Outv;
        const size_t rr = (size_t)mrow * Ncols;
        O[rr + colA]      = __float2bfloat16(gelu_fast(v0));
        O[rr + colA + 16] = __float2bfloat16(gelu_fast(v1));
      } else {
        float* O = (float*)Outv;
        const size_t rr = (size_t)mrow * Ncols;
        O[rr + colA]      = resid[rr + colA]      + v0;
        O[rr + colA + 16] = resid[rr + colA + 16] + v1;
      }
    }
  }
}

// ---------------- MFMA windowed attention: one wave per (window, head) ----------------
__global__ __launch_bounds__(64)
void attn_mfma_kernel(const __hip_bfloat16* __restrict__ qkv,
                      const float* __restrict__ bias2,
                      __hip_bfloat16* __restrict__ attnout)
{
  __shared__ unsigned short VT[32 * 72];   // V^T [d][tok], stride 72
  __shared__ unsigned short Pl[64 * 72];   // P  [i][j],   stride 72

  const int bid = blockIdx.x;
  const int w = bid / 6, h = bid - (bid / 6) * 6;
  const int lane = threadIdx.x;
  const int lr = lane & 15, lg = lane >> 4;
  const int nw = w & 63;
  const int wt = (((nw >> 3) == 7) ? 2 : 0) + (((nw & 7) == 7) ? 1 : 0);
  const unsigned short* Q = (const unsigned short*)qkv;
  const size_t rowbase = (size_t)w * 49 * 576;
  const float scale = 0.17677669529663687f;

  for (int e = lane; e < 196; e += 64) {
    int t = e % 49, c = e / 49;
    uint4 v = *(const uint4*)(Q + rowbase + (size_t)t * 576 + 384 + h * 32 + c * 8);
    unsigned va[4] = {v.x, v.y, v.z, v.w};
    #pragma unroll
    for (int q = 0; q < 4; ++q) {
      VT[(c * 8 + q * 2    ) * 72 + t] = (unsigned short)(va[q] & 0xffff);
      VT[(c * 8 + q * 2 + 1) * 72 + t] = (unsigned short)(va[q] >> 16);
    }
  }
  for (int e = lane; e < 32 * 15; e += 64) {
    int d = e / 15, t = 49 + e - (e / 15) * 15;
    VT[d * 72 + t] = 0;
  }

  bf16x8 qf[4], kf[4];
  #pragma unroll
  for (int it = 0; it < 4; ++it) {
    int tok = it * 16 + lr; if (tok > 48) tok = 48;
    qf[it] = *(const bf16x8*)(Q + rowbase + (size_t)tok * 576 + h * 32 + lg * 8);
  }
  #pragma unroll
  for (int jt = 0; jt < 4; ++jt) {
    int tok = jt * 16 + lr; if (tok > 48) tok = 48;
    kf[jt] = *(const bf16x8*)(Q + rowbase + (size_t)tok * 576 + 192 + h * 32 + lg * 8);
  }

  f32x4 acc[4][4] = {};
  #pragma unroll
  for (int jt = 0; jt < 4; ++jt)
    #pragma unroll
    for (int it = 0; it < 4; ++it)
      acc[jt][it] = __builtin_amdgcn_mfma_f32_16x16x32_bf16(kf[jt], qf[it], acc[jt][it], 0, 0, 0);

  __syncthreads();

  const float* brow = bias2 + ((size_t)(wt * 6 + h) * 64) * 64;
  #pragma unroll
  for (int it = 0; it < 4; ++it) {
    const int i = it * 16 + lr;
    float s[4][4];
    #pragma unroll
    for (int jt = 0; jt < 4; ++jt) {
      float4 bv = *(const float4*)(brow + (size_t)i * 64 + jt * 16 + lg * 4);
      s[jt][0] = fmaf(acc[jt][it][0], scale, bv.x);
      s[jt][1] = fmaf(acc[jt][it][1], scale, bv.y);
      s[jt][2] = fmaf(acc[jt][it][2], scale, bv.z);
      s[jt][3] = fmaf(acc[jt][it][3], scale, bv.w);
    }
    float mx = s[0][0];
    #pragma unroll
    for (int jt = 0; jt < 4; ++jt)
      #pragma unroll
      for (int r = 0; r < 4; ++r) mx = fmaxf(mx, s[jt][r]);
    mx = fmaxf(mx, __shfl_xor(mx, 16));
    mx = fmaxf(mx, __shfl_xor(mx, 32));
    float sum = 0.0f;
    #pragma unroll
    for (int jt = 0; jt < 4; ++jt)
      #pragma unroll
      for (int r = 0; r < 4; ++r) { s[jt][r] = __expf(s[jt][r] - mx); sum += s[jt][r]; }
    sum += __shfl_xor(sum, 16);
    sum += __shfl_xor(sum, 32);
    const float inv = 1.0f / sum;
    #pragma unroll
    for (int jt = 0; jt < 4; ++jt) {
      unsigned lo = (unsigned)f2bu(s[jt][0] * inv) | ((unsigned)f2bu(s[jt][1] * inv) << 16);
      unsigned hi = (unsigned)f2bu(s[jt][2] * inv) | ((unsigned)f2bu(s[jt][3] * inv) << 16);
      uint2 val; val.x = lo; val.y = hi;
      *(uint2*)&Pl[i * 72 + jt * 16 + lg * 4] = val;
    }
  }

  __syncthreads();

  f32x4 o[4][2] = {};
  #pragma unroll
  for (int ks = 0; ks < 2; ++ks) {
    bf16x8 pa[4], vb[2];
    #pragma unroll
    for (int it = 0; it < 4; ++it)
      pa[it] = *(const bf16x8*)&Pl[(it * 16 + lr) * 72 + ks * 32 + lg * 8];
    #pragma unroll
    for (int nt = 0; nt < 2; ++nt)
      vb[nt] = *(const bf16x8*)&VT[(nt * 16 + lr) * 72 + ks * 32 + lg * 8];
    #pragma unroll
    for (int it = 0; it < 4; ++it) {
      o[it][0] = __builtin_amdgcn_mfma_f32_16x16x32_bf16(pa[it], vb[0], o[it][0], 0, 0, 0);
      o[it][1] = __builtin_amdgcn_mfma_f32_16x16x32_bf16(pa[it], vb[1], o[it][1], 0, 0, 0);
    }
  }

  #pragma unroll
  for (int it = 0; it < 4; ++it) {
    #pragma unroll
    for (int r = 0; r < 4; ++r) {
      int i = it * 16 + lg * 4 + r;
      if (i < 49) {
        size_t dst = ((size_t)w * 49 + i) * 192 + h * 32;
        attnout[dst + lr]      = __float2bfloat16(o[it][0][r]);
        attnout[dst + 16 + lr] = __float2bfloat16(o[it][1][r]);
      }
    }
  }
}

// ---------------- launcher ----------------
extern "C" void kernel_launch(void* const* d_in, const int* in_sizes, int n_in,
                              void* d_out, int out_size, void* d_ws, size_t ws_size,
                              hipStream_t stream)
{
  const float* x        = (const float*)d_in[0];
  const float* n1g      = (const float*)d_in[1];
  const float* n1b      = (const float*)d_in[2];
  const float* qkv_w    = (const float*)d_in[3];
  const float* qkv_b    = (const float*)d_in[4];
  const float* btab     = (const float*)d_in[5];
  const float* proj_w   = (const float*)d_in[6];
  const float* proj_b   = (const float*)d_in[7];
  const float* n2g      = (const float*)d_in[8];
  const float* n2b      = (const float*)d_in[9];
  const float* fc1_w    = (const float*)d_in[10];
  const float* fc1_b    = (const float*)d_in[11];
  const float* fc2_w    = (const float*)d_in[12];
  const float* fc2_b    = (const float*)d_in[13];
  float* out = (float*)d_out;

  char* ws = (char*)d_ws;
  const size_t szA = (size_t)CM * CC * 2;
  const size_t szB = (size_t)CM * CHID * 2;
  __hip_bfloat16* bufA = (__hip_bfloat16*)ws;                  // xw -> attnout -> h2
  __hip_bfloat16* bufB = (__hip_bfloat16*)(ws + szA);          // qkv -> hmid
  __hip_bfloat16* wq   = (__hip_bfloat16*)(ws + szA + szB);    // [576][192]
  __hip_bfloat16* wp   = wq + 576 * 192;                       // [192][192]
  __hip_bfloat16* w1   = wp + 192 * 192;                       // [768][192]
  __hip_bfloat16* w2   = w1 + 768 * 192;                       // [192][768]
  float* bias2         = (float*)(w2 + 192 * 768);             // [4][6][64][64] f32

  // 0. one-shot prep (4 weight transposes + bias2 table)
  prep_kernel<<<(110592 + 36864 + 147456 + 147456 + 98304 + 255) / 256, 256, 0, stream>>>(
      qkv_w, proj_w, fc1_w, fc2_w, btab, wq, wp, w1, w2, bias2);

  // 1. LN1 + roll + window partition -> xw (bf16)
  ln_kernel<true><<<CM / 4, 256, 0, stream>>>(x, n1g, n1b, bufA);
  // 2. qkv = xw @ qkv_w + qkv_b -> bf16 [CM,576]
  gemm_mfma<0><<<dim3(576 / 64, CM / 128), 256, 0, stream>>>(bufA, wq, qkv_b, bufB, nullptr, CC, 576);
  // 3. MFMA windowed attention -> attnout (bf16, reuses bufA)
  attn_mfma_kernel<<<2048 * 6, 64, 0, stream>>>(bufB, bias2, bufA);
  // 4. proj + window reverse + roll + residual -> x2 into d_out (f32)
  gemm_mfma<1><<<dim3(192 / 64, CM / 128), 256, 0, stream>>>(bufA, wp, proj_b, out, x, CC, 192);
  // 5. LN2 on x2 -> h2 (bf16, bufA)
  ln_kernel<false><<<CM / 4, 256, 0, stream>>>(out, n2g, n2b, bufA);
  // 6. fc1 + gelu -> hmid (bf16, bufB)
  gemm_mfma<2><<<dim3(CHID / 64, CM / 128), 256, 0, stream>>>(bufA, w1, fc1_b, bufB, nullptr, CC, CHID);
  // 7. fc2 + in-place residual: out += hmid @ fc2_w + fc2_b
  gemm_mfma<3><<<dim3(192 / 64, CM / 128), 256, 0, stream>>>(bufB, w2, fc2_b, out, out, CHID, 192);
}